// Round 6
// baseline (186.099 us; speedup 1.0000x reference)
//
#include <hip/hip_runtime.h>
#include <math.h>

#define NTOK 384
#define DIM  128
#define HEADS 4
#define DHEAD 64
#define INNER 256
#define DEPTH 3
#define EDGE 8
#define FFD 512

__device__ __forceinline__ float wave_sum64(float v){
#pragma unroll
  for (int m = 32; m >= 1; m >>= 1) v += __shfl_xor(v, m, 64);
  return v;
}
__device__ __forceinline__ float wave_max64(float v){
#pragma unroll
  for (int m = 32; m >= 1; m >>= 1) v = fmaxf(v, __shfl_xor(v, m, 64));
  return v;
}

// Barrier that orders LDS only — does NOT drain outstanding global (vmcnt) loads,
// so cross-phase weight prefetches keep streaming. (HK/T4 pattern.)
__device__ __forceinline__ void bar_lgkm(){
  asm volatile("s_waitcnt lgkmcnt(0)" ::: "memory");
  __builtin_amdgcn_s_barrier();
}

// XCD-pinned row mapping: 384 = 8 XCDs x 48 rows.
__device__ __forceinline__ int swz_row(int id){ return (id & 7) * 48 + (id >> 3); }

// Rotary tables, matching numpy float32 semantics via double precision then round.
__global__ void k_rotary(float* __restrict__ cosS, float* __restrict__ sinS){
  int i = blockIdx.x;
  int t = threadIdx.x;     // d in [0,64)
  int j = t >> 1;
  double ex = (double)(2 * j) / 64.0;
  float p = (float)pow(10000.0, ex);
  float inv = 1.0f / p;
  float f = (float)i * inv;
  double fd = (double)f;
  cosS[i * 64 + t] = (float)cos(fd);
  sinS[i * 64 + t] = (float)sin(fd);
}

// QKV (+rotary, qWe, qbe) for ONE row, 1024 threads, 2-way K-split.
__device__ __forceinline__ void qkv_row_1024(
    int i, int t, const float* __restrict__ snx,
    const float* __restrict__ Wq, const float* __restrict__ bq,
    const float* __restrict__ Wkv, const float* __restrict__ bkv,
    const float* __restrict__ We, const float* __restrict__ be,
    const float* __restrict__ cosS, const float* __restrict__ sinS,
    float* __restrict__ qb_, float* __restrict__ kbT, float* __restrict__ vb_,
    float* __restrict__ qWeB, float* __restrict__ qbeB,
    float* __restrict__ qpart)   // LDS, 768 floats
{
  int half = t >> 9;           // 0: k in [0,64), 1: [64,128)
  int task = t & 511;
  float a0 = 0.f, a1 = 0.f;
  if (task < 384){
    const float2* Wp; int stride;
    if (task < 128)      { Wp = (const float2*)Wq + task;              stride = 128; }
    else if (task < 256) { Wp = (const float2*)Wkv + (task - 128);     stride = 256; }
    else                 { Wp = (const float2*)Wkv + 128 + (task - 256); stride = 256; }
    int k0 = half * 64;
#pragma unroll 8
    for (int kk = 0; kk < 64; ++kk){
      int k = k0 + kk;
      float2 w = Wp[(size_t)k * stride];
      float xr = snx[k];
      a0 = fmaf(xr, w.x, a0); a1 = fmaf(xr, w.y, a1);
    }
    if (half == 1){ qpart[task * 2] = a0; qpart[task * 2 + 1] = a1; }
  }
  bar_lgkm();
  if (half == 0 && task < 384){
    a0 += qpart[task * 2]; a1 += qpart[task * 2 + 1];
    int pcol;
    const float* bb;
    if (task < 128)      { pcol = task;       bb = bq; }
    else if (task < 256) { pcol = task - 128; bb = bkv; }
    else                 { pcol = task - 256; bb = bkv + 256; }
    a0 += bb[2 * pcol]; a1 += bb[2 * pcol + 1];

    if (task < 256){
      int dloc = (2 * pcol) & 63;
      float c = cosS[i * 64 + dloc], s = sinS[i * 64 + dloc];
      float r0 = a0 * c - a1 * s;
      float r1 = a1 * c + a0 * s;
      if (task < 128){
        qb_[i * 256 + 2 * pcol]     = r0;
        qb_[i * 256 + 2 * pcol + 1] = r1;
        int h = pcol >> 5;
#pragma unroll
        for (int cc = 0; cc < 8; ++cc){
          float pr = r0 * We[cc * 256 + 2 * pcol] + r1 * We[cc * 256 + 2 * pcol + 1];
#pragma unroll
          for (int m = 16; m >= 1; m >>= 1) pr += __shfl_xor(pr, m, 32);
          if ((t & 31) == 0) qWeB[(h * NTOK + i) * 8 + cc] = pr;
        }
        float pb = r0 * be[2 * pcol] + r1 * be[2 * pcol + 1];
#pragma unroll
        for (int m = 16; m >= 1; m >>= 1) pb += __shfl_xor(pb, m, 32);
        if ((t & 31) == 0) qbeB[h * NTOK + i] = pb;
      } else {
        int h = pcol >> 5, d0 = 2 * (pcol & 31);
        kbT[(size_t)(h * 64 + d0) * NTOK + i]     = r0;
        kbT[(size_t)(h * 64 + d0 + 1) * NTOK + i] = r1;
      }
    } else {
      vb_[i * 256 + 2 * pcol]     = a0;
      vb_[i * 256 + 2 * pcol + 1] = a1;
    }
  }
}

// Layer-0 LN1 + QKV. One row per block, 1024 threads.
__global__ __launch_bounds__(1024) void k_lnqkv(
    const float* __restrict__ x,
    const float* __restrict__ ls, const float* __restrict__ lb,
    const float* __restrict__ Wq, const float* __restrict__ bq,
    const float* __restrict__ Wkv, const float* __restrict__ bkv,
    const float* __restrict__ We, const float* __restrict__ be,
    const float* __restrict__ cosS, const float* __restrict__ sinS,
    float* __restrict__ qb_, float* __restrict__ kbT, float* __restrict__ vb_,
    float* __restrict__ qWeB, float* __restrict__ qbeB)
{
  __shared__ float snx[128];
  __shared__ float red[4];
  __shared__ float qpart[768];
  int i = swz_row(blockIdx.x);
  int t = threadIdx.x;
  float xv = (t < 128) ? x[(size_t)i * 128 + t] : 0.f;
  float s = (t < 128) ? wave_sum64(xv) : 0.f;
  if (t == 0)  red[0] = s;
  if (t == 64) red[1] = s;
  bar_lgkm();
  float mu = (red[0] + red[1]) * (1.0f / 128.0f);
  float d = xv - mu;
  float s2 = (t < 128) ? wave_sum64(d * d) : 0.f;
  if (t == 0)  red[2] = s2;
  if (t == 64) red[3] = s2;
  bar_lgkm();
  if (t < 128){
    float var = (red[2] + red[3]) * (1.0f / 128.0f);
    float rstd = 1.0f / sqrtf(var + 1e-3f);
    snx[t] = d * rstd * ls[t] + lb[t];
  }
  bar_lgkm();
  qkv_row_1024(i, t, snx, Wq, bq, Wkv, bkv, We, be, cosS, sinS,
               qb_, kbT, vb_, qWeB, qbeB, qpart);
}

// Attention for one (i, h). 384 threads, thread t <-> j=t. K is transposed.
__global__ __launch_bounds__(384) void k_attn(
    const float* __restrict__ qb_, const float* __restrict__ kbT, const float* __restrict__ vb_,
    const float* __restrict__ qWeB, const float* __restrict__ qbeB,
    const float* __restrict__ edges,
    const float* __restrict__ We, const float* __restrict__ be,
    float* __restrict__ aout)
{
  __shared__ float qs[64];
  __shared__ float qw[8];
  __shared__ float qbs_s;
  __shared__ float attnL[NTOK];
  __shared__ float redA[6], redB[6];
  __shared__ float red8[6][8];
  __shared__ float aws[8];
  __shared__ float part[NTOK];

  int id = blockIdx.x;           // 1536 = 8 xcd * (48 rows * 4 heads)
  int xcd = id & 7, loc = id >> 3;
  int i = xcd * 48 + (loc % 48);
  int h = loc / 48;
  int t = threadIdx.x, lane = t & 63, wv = t >> 6;

  if (t < 64) qs[t] = qb_[i * 256 + h * 64 + t];
  else if (t < 72) qw[t - 64] = qWeB[(h * NTOK + i) * 8 + (t - 64)];
  else if (t == 72) qbs_s = qbeB[h * NTOK + i];
  __syncthreads();

  // ---- sim for j = t: coalesced reads of kbT[h][d][j]
  const float* kTp = kbT + (size_t)(h * 64) * NTOK + t;
  float ac0 = 0.f, ac1 = 0.f, ac2 = 0.f, ac3 = 0.f;
#pragma unroll 8
  for (int d = 0; d < 64; d += 4){
    ac0 = fmaf(qs[d],     kTp[(size_t)d * NTOK],       ac0);
    ac1 = fmaf(qs[d + 1], kTp[(size_t)(d + 1) * NTOK], ac1);
    ac2 = fmaf(qs[d + 2], kTp[(size_t)(d + 2) * NTOK], ac2);
    ac3 = fmaf(qs[d + 3], kTp[(size_t)(d + 3) * NTOK], ac3);
  }
  const float* ep = edges + ((size_t)i * NTOK + t) * 8;
  float4 e0 = *(const float4*)ep;
  float4 e1 = *(const float4*)(ep + 4);
  float ed = e0.x * qw[0] + e0.y * qw[1] + e0.z * qw[2] + e0.w * qw[3]
           + e1.x * qw[4] + e1.y * qw[5] + e1.z * qw[6] + e1.w * qw[7];
  float sim = 0.125f * (ac0 + ac1 + ac2 + ac3 + ed + qbs_s);

  // ---- softmax over 384 (6 waves)
  float mx = wave_max64(sim);
  if (lane == 0) redA[wv] = mx;
  __syncthreads();
  float gm = fmaxf(fmaxf(fmaxf(redA[0], redA[1]), fmaxf(redA[2], redA[3])),
                   fmaxf(redA[4], redA[5]));
  float e = expf(sim - gm);
  float sm = wave_sum64(e);
  if (lane == 0) redB[wv] = sm;
  __syncthreads();
  float tot = redB[0] + redB[1] + redB[2] + redB[3] + redB[4] + redB[5];
  float w = e / tot;
  attnL[t] = w;

  // ---- aw[c] = sum_j w[j]*edges[i,j,c]
  float a8[8] = { w * e0.x, w * e0.y, w * e0.z, w * e0.w,
                  w * e1.x, w * e1.y, w * e1.z, w * e1.w };
#pragma unroll
  for (int cc = 0; cc < 8; ++cc){
    float r = wave_sum64(a8[cc]);
    if (lane == 0) red8[wv][cc] = r;
  }
  __syncthreads();
  if (t < 8){
    float sa = 0.f;
#pragma unroll
    for (int g = 0; g < 6; ++g) sa += red8[g][t];
    aws[t] = sa;
  }
  __syncthreads();

  // ---- out[d] = sum_j attn[j]*v[j,d]  (6-way j split)
  {
    int dd = lane;
    const float* vp = vb_ + h * 64 + dd;
    int j0 = wv * 64;
    float va = 0.f, vb2 = 0.f;
#pragma unroll 8
    for (int jj = 0; jj < 64; jj += 2){
      va  = fmaf(attnL[j0 + jj],     vp[(size_t)(j0 + jj) * 256],     va);
      vb2 = fmaf(attnL[j0 + jj + 1], vp[(size_t)(j0 + jj + 1) * 256], vb2);
    }
    part[t] = va + vb2;
  }
  __syncthreads();
  if (t < 64){
    float o = part[t] + part[64 + t] + part[128 + t] + part[192 + t]
            + part[256 + t] + part[320 + t];
    float ew = 0.f;
#pragma unroll
    for (int cc = 0; cc < 8; ++cc) ew = fmaf(aws[cc], We[cc * 256 + h * 64 + t], ew);
    o += ew + be[h * 64 + t];
    aout[i * 256 + h * 64 + t] = o;
  }
}

// Fused tail with cross-phase weight streaming (raw barriers, no vmcnt drain).
__global__ __launch_bounds__(1024) void k_tail(
    const float* __restrict__ aout,
    const float* __restrict__ Wo, const float* __restrict__ bo,
    const float* __restrict__ Wg_a,
    const float* __restrict__ ln2s, const float* __restrict__ ln2b,
    const float* __restrict__ W1, const float* __restrict__ b1,
    const float* __restrict__ W2, const float* __restrict__ b2,
    const float* __restrict__ Wg_f,
    const float* __restrict__ xin, float* __restrict__ xout,
    int has_next,
    const float* __restrict__ ls_n, const float* __restrict__ lb_n,
    const float* __restrict__ Wq_n, const float* __restrict__ bq_n,
    const float* __restrict__ Wkv_n, const float* __restrict__ bkv_n,
    const float* __restrict__ We_n, const float* __restrict__ be_n,
    const float* __restrict__ cosS, const float* __restrict__ sinS,
    float* __restrict__ qb_, float* __restrict__ kbT, float* __restrict__ vb_,
    float* __restrict__ qWeB, float* __restrict__ qbeB)
{
  __shared__ float ar[256];
  __shared__ float xold[128];
  __shared__ float xrow[128];
  __shared__ float snx[128];
  __shared__ float hs[512];
  __shared__ float4 prL[1024];
  __shared__ float red[4];
  __shared__ float qpart[768];
  float* prF = (float*)prL;

  int i = swz_row(blockIdx.x);
  int t = threadIdx.x;
  int colq = t & 31, ksub = t >> 5;      // proj / FFN2 mapping
  int colq1 = t & 127, ksub1 = t >> 7;   // FFN1 mapping

  // ---- phase 1: issue proj weights + stage activations
  float4 wo[8];
  const float4* Wo4 = (const float4*)Wo;
#pragma unroll
  for (int kk = 0; kk < 8; ++kk)
    wo[kk] = Wo4[(size_t)(ksub * 8 + kk) * 32 + colq];
  if (t < 64)      ((float4*)ar)[t]        = ((const float4*)(aout + (size_t)i * 256))[t];
  else if (t < 96) ((float4*)xold)[t - 64] = ((const float4*)(xin  + (size_t)i * 128))[t - 64];
  bar_lgkm();

  // ---- phase 2: proj FMAs; then issue FFN1 weights (stream through phase 3)
  {
    float4 acc = {0.f, 0.f, 0.f, 0.f};
#pragma unroll
    for (int kk = 0; kk < 8; ++kk){
      float a = ar[ksub * 8 + kk];
      acc.x = fmaf(a, wo[kk].x, acc.x); acc.y = fmaf(a, wo[kk].y, acc.y);
      acc.z = fmaf(a, wo[kk].z, acc.z); acc.w = fmaf(a, wo[kk].w, acc.w);
    }
    prL[ksub * 32 + colq] = acc;
  }
  float4 w1r[16];
  const float4* W14 = (const float4*)W1;
#pragma unroll
  for (int kk = 0; kk < 16; ++kk)
    w1r[kk] = W14[(size_t)(ksub1 * 16 + kk) * 128 + colq1];
  bar_lgkm();

  // ---- phase 3: reduce + gate_a + LN2 (2 waves; FFN1 weights streaming)
  float o = 0.f, xv2 = 0.f, dcen = 0.f;
  if (t < 128){
    o = bo[t];
#pragma unroll
    for (int s = 0; s < 32; ++s) o += prF[s * 128 + t];
    float xo = xold[t];
    float gp = o * Wg_a[t] + xo * Wg_a[128 + t] + (o - xo) * Wg_a[256 + t];
    float sg = wave_sum64(gp);
    if (t == 0)  red[0] = sg;
    if (t == 64) red[1] = sg;
  }
  bar_lgkm();
  if (t < 128){
    float z = red[0] + red[1];
    float gg = 1.0f / (1.0f + expf(-z));
    xv2 = o * gg + xold[t] * (1.0f - gg);
    xrow[t] = xv2;
    float s = wave_sum64(xv2);
    if (t == 0)  red[2] = s;
    if (t == 64) red[3] = s;
  }
  bar_lgkm();
  if (t < 128){
    float mu = (red[2] + red[3]) * (1.0f / 128.0f);
    dcen = xv2 - mu;
    float s2 = wave_sum64(dcen * dcen);
    if (t == 0)  red[0] = s2;
    if (t == 64) red[1] = s2;
  }
  bar_lgkm();
  if (t < 128){
    float var = (red[0] + red[1]) * (1.0f / 128.0f);
    float rstd = 1.0f / sqrtf(var + 1e-3f);
    snx[t] = dcen * rstd * ln2s[t] + ln2b[t];
  }
  bar_lgkm();

  // ---- phase 4: FFN1 FMAs; then issue FFN2 weights (stream through phase 5)
  {
    float4 acc = {0.f, 0.f, 0.f, 0.f};
#pragma unroll
    for (int kk = 0; kk < 16; ++kk){
      float a = snx[ksub1 * 16 + kk];
      acc.x = fmaf(a, w1r[kk].x, acc.x); acc.y = fmaf(a, w1r[kk].y, acc.y);
      acc.z = fmaf(a, w1r[kk].z, acc.z); acc.w = fmaf(a, w1r[kk].w, acc.w);
    }
    prL[ksub1 * 128 + colq1] = acc;
  }
  float4 w2r[16];
  const float4* W24 = (const float4*)W2;
#pragma unroll
  for (int kk = 0; kk < 16; ++kk)
    w2r[kk] = W24[(size_t)(ksub * 16 + kk) * 32 + colq];
  bar_lgkm();

  // ---- phase 5: GELU reduce -> hs (512 threads; FFN2 weights streaming)
  if (t < 512){
    float h = b1[t];
#pragma unroll
    for (int s3 = 0; s3 < 8; ++s3) h += prF[s3 * 512 + t];
    const float RS2 = 0.70710678118654752440f;
    hs[t] = 0.5f * h * (1.0f + erff(h * RS2));
  }
  bar_lgkm();

  // ---- phase 6: FFN2 FMAs
  {
    float4 acc = {0.f, 0.f, 0.f, 0.f};
#pragma unroll
    for (int kk = 0; kk < 16; ++kk){
      float a = hs[ksub * 16 + kk];
      acc.x = fmaf(a, w2r[kk].x, acc.x); acc.y = fmaf(a, w2r[kk].y, acc.y);
      acc.z = fmaf(a, w2r[kk].z, acc.z); acc.w = fmaf(a, w2r[kk].w, acc.w);
    }
    prL[ksub * 32 + colq] = acc;
  }
  bar_lgkm();

  // ---- phase 7: reduce + gate_f + xnew (+ next LN1)
  float f = 0.f, xnew = 0.f, dn = 0.f;
  if (t < 128){
    f = b2[t];
#pragma unroll
    for (int s3 = 0; s3 < 32; ++s3) f += prF[s3 * 128 + t];
    float xr = xrow[t];
    float gp = f * Wg_f[t] + xr * Wg_f[128 + t] + (f - xr) * Wg_f[256 + t];
    float sg = wave_sum64(gp);
    if (t == 0)  red[0] = sg;
    if (t == 64) red[1] = sg;
  }
  bar_lgkm();
  if (t < 128){
    float z = red[0] + red[1];
    float gg = 1.0f / (1.0f + expf(-z));
    xnew = f * gg + xrow[t] * (1.0f - gg);
    xout[(size_t)i * 128 + t] = xnew;
  }
  if (has_next){
    float sn = (t < 128) ? wave_sum64(xnew) : 0.f;
    if (t == 0)  red[2] = sn;
    if (t == 64) red[3] = sn;
    bar_lgkm();
    if (t < 128){
      float mun = (red[2] + red[3]) * (1.0f / 128.0f);
      dn = xnew - mun;
      float sn2 = wave_sum64(dn * dn);
      if (t == 0)  red[0] = sn2;
      if (t == 64) red[1] = sn2;
    }
    bar_lgkm();
    if (t < 128){
      float var = (red[0] + red[1]) * (1.0f / 128.0f);
      float rstd = 1.0f / sqrtf(var + 1e-3f);
      snx[t] = dn * rstd * ls_n[t] + lb_n[t];
    }
    bar_lgkm();
    qkv_row_1024(i, t, snx, Wq_n, bq_n, Wkv_n, bkv_n, We_n, be_n, cosS, sinS,
                 qb_, kbT, vb_, qWeB, qbeB, qpart);
  }
}

// Final head. Single block, 384 threads, float4 x loads.
__global__ __launch_bounds__(384) void k_final(
    const float* __restrict__ x,
    const float* __restrict__ Wd1, const float* __restrict__ bd1,
    const float* __restrict__ Wd2, const float* __restrict__ bd2,
    float* __restrict__ out)
{
  __shared__ float red[6];
  int i = threadIdx.x;
  float y[9];
#pragma unroll
  for (int c = 0; c < 9; ++c) y[c] = bd1[c];
  const float4* x4 = (const float4*)(x + (size_t)i * 128);
#pragma unroll 8
  for (int r4 = 0; r4 < 32; ++r4){
    float4 xv = x4[r4];
    const float* wp = Wd1 + (r4 * 4) * 9;
#pragma unroll
    for (int c = 0; c < 9; ++c) y[c] = fmaf(xv.x, wp[c], y[c]);
#pragma unroll
    for (int c = 0; c < 9; ++c) y[c] = fmaf(xv.y, wp[9 + c], y[c]);
#pragma unroll
    for (int c = 0; c < 9; ++c) y[c] = fmaf(xv.z, wp[18 + c], y[c]);
#pragma unroll
    for (int c = 0; c < 9; ++c) y[c] = fmaf(xv.w, wp[27 + c], y[c]);
  }
#pragma unroll
  for (int c = 0; c < 9; ++c) y[c] = fmaxf(y[c], 0.0f);
  float z[3];
#pragma unroll
  for (int c = 0; c < 3; ++c){
    float a = bd2[c];
#pragma unroll
    for (int r = 0; r < 9; ++r) a = fmaf(y[r], Wd2[r * 3 + c], a);
    z[c] = a;
  }
#pragma unroll
  for (int c = 0; c < 3; ++c){
    float s = wave_sum64(z[c]);
    if ((i & 63) == 0) red[i >> 6] = s;
    __syncthreads();
    float tot = 0.f;
#pragma unroll
    for (int w = 0; w < 6; ++w) tot += red[w];
    float mean = tot * (1.0f / 384.0f);
    out[i * 3 + c] = z[c] - mean;
    __syncthreads();
  }
}

extern "C" void kernel_launch(void* const* d_in, const int* in_sizes, int n_in,
                              void* d_out, int out_size, void* d_ws, size_t ws_size,
                              hipStream_t stream)
{
  const float* nodes   = (const float*)d_in[0];
  const float* edges   = (const float*)d_in[1];
  const float* ln1_s   = (const float*)d_in[2];
  const float* ln1_b   = (const float*)d_in[3];
  const float* Wq      = (const float*)d_in[4];
  const float* bq      = (const float*)d_in[5];
  const float* Wkv     = (const float*)d_in[6];
  const float* bkv     = (const float*)d_in[7];
  const float* We      = (const float*)d_in[8];
  const float* be      = (const float*)d_in[9];
  const float* Wo      = (const float*)d_in[10];
  const float* bo      = (const float*)d_in[11];
  const float* Wg_attn = (const float*)d_in[12];
  const float* ln2_s   = (const float*)d_in[13];
  const float* ln2_b   = (const float*)d_in[14];
  const float* W1      = (const float*)d_in[15];
  const float* b1      = (const float*)d_in[16];
  const float* W2      = (const float*)d_in[17];
  const float* b2      = (const float*)d_in[18];
  const float* Wg_ff   = (const float*)d_in[19];
  const float* Wd1     = (const float*)d_in[20];
  const float* bd1     = (const float*)d_in[21];
  const float* Wd2     = (const float*)d_in[22];
  const float* bd2     = (const float*)d_in[23];
  // d_in[24] = mask: all-true; no-op in the math.

  float* ws   = (float*)d_ws;
  float* cosS = ws;                 // 384*64
  float* sinS = cosS + 24576;
  float* qbuf = sinS + 24576;       // 384*256
  float* kbT  = qbuf + 98304;       // [4][64][384]
  float* vbuf = kbT + 98304;
  float* qWeB = vbuf + 98304;       // 4*384*8
  float* qbeB = qWeB + 12288;       // 4*384
  float* aoutB = qbeB + 1536;       // 384*256
  float* xbuf = aoutB + 98304;      // 384*128

  k_rotary<<<dim3(NTOK), dim3(64), 0, stream>>>(cosS, sinS);

  k_lnqkv<<<dim3(NTOK), dim3(1024), 0, stream>>>(
      nodes, ln1_s, ln1_b, Wq, bq, Wkv, bkv, We, be,
      cosS, sinS, qbuf, kbT, vbuf, qWeB, qbeB);

  for (int L = 0; L < DEPTH; ++L){
    int Ln = (L < DEPTH - 1) ? (L + 1) : L;
    k_attn<<<dim3(NTOK * HEADS), dim3(384), 0, stream>>>(
        qbuf, kbT, vbuf, qWeB, qbeB, edges,
        We + (size_t)L * EDGE * INNER, be + L * INNER, aoutB);
    k_tail<<<dim3(NTOK), dim3(1024), 0, stream>>>(
        aoutB, Wo + (size_t)L * INNER * DIM, bo + L * DIM,
        Wg_attn + L * 3 * DIM,
        ln2_s + L * DIM, ln2_b + L * DIM,
        W1 + (size_t)L * DIM * FFD, b1 + L * FFD,
        W2 + (size_t)L * FFD * DIM, b2 + L * DIM,
        Wg_ff + L * 3 * DIM,
        (L == 0) ? nodes : xbuf, xbuf,
        (L < DEPTH - 1) ? 1 : 0,
        ln1_s + Ln * DIM, ln1_b + Ln * DIM,
        Wq + (size_t)Ln * DIM * INNER, bq + Ln * INNER,
        Wkv + (size_t)Ln * DIM * 2 * INNER, bkv + Ln * 2 * INNER,
        We + (size_t)Ln * EDGE * INNER, be + Ln * INNER,
        cosS, sinS, qbuf, kbT, vbuf, qWeB, qbeB);
  }

  k_final<<<dim3(1), dim3(384), 0, stream>>>(xbuf, Wd1, bd1, Wd2, bd2, (float*)d_out);
}

// Round 7
// 153.941 us; speedup vs baseline: 1.2089x; 1.2089x over previous
//
#include <hip/hip_runtime.h>
#include <math.h>

#define NTOK 384
#define DIM  128
#define HEADS 4
#define DHEAD 64
#define INNER 256
#define DEPTH 3
#define EDGE 8
#define FFD 512

__device__ __forceinline__ float wave_sum64(float v){
#pragma unroll
  for (int m = 32; m >= 1; m >>= 1) v += __shfl_xor(v, m, 64);
  return v;
}
__device__ __forceinline__ float wave_max64(float v){
#pragma unroll
  for (int m = 32; m >= 1; m >>= 1) v = fmaxf(v, __shfl_xor(v, m, 64));
  return v;
}

// XCD-pinned row mapping: 384 = 8 XCDs x 48 rows.
__device__ __forceinline__ int swz_row(int id){ return (id & 7) * 48 + (id >> 3); }

// Rotary for one (i, d): numpy float32 semantics via double precision then round.
__device__ __forceinline__ void rotary_val(int i, int d, float* c, float* s){
  int j = d >> 1;
  double ex = (double)(2 * j) / 64.0;
  float p = (float)pow(10000.0, ex);
  float inv = 1.0f / p;
  float f = (float)i * inv;
  double fd = (double)f;
  *c = (float)cos(fd);
  *s = (float)sin(fd);
}

// QKV (+rotary, qWe, qbe) for ONE row. t<384 active (any block >=384 thr).
// Full K=128 per thread. K written transposed to kbT[h][d][j].
__device__ __forceinline__ void qkv_row_512(
    int i, int t, const float* __restrict__ snx,
    const float* __restrict__ Wq, const float* __restrict__ bq,
    const float* __restrict__ Wkv, const float* __restrict__ bkv,
    const float* __restrict__ We, const float* __restrict__ be,
    const float* __restrict__ cosRow, const float* __restrict__ sinRow,
    float* __restrict__ qb_, float* __restrict__ kbT, float* __restrict__ vb_,
    float* __restrict__ qWeB, float* __restrict__ qbeB)
{
  if (t >= 384) return;
  const float2* Wp; const float* bb; int pcol; int stride;
  if (t < 128)      { Wp = (const float2*)Wq + t;              stride = 128; bb = bq;        pcol = t; }
  else if (t < 256) { Wp = (const float2*)Wkv + (t - 128);     stride = 256; bb = bkv;       pcol = t - 128; }
  else              { Wp = (const float2*)Wkv + 128 + (t - 256); stride = 256; bb = bkv + 256; pcol = t - 256; }

  float a0 = 0.f, a1 = 0.f;
#pragma unroll 8
  for (int k = 0; k < 128; ++k){
    float2 w = Wp[(size_t)k * stride];
    float xr = snx[k];
    a0 = fmaf(xr, w.x, a0); a1 = fmaf(xr, w.y, a1);
  }
  a0 += bb[2 * pcol]; a1 += bb[2 * pcol + 1];

  if (t < 256){
    int dloc = (2 * pcol) & 63;
    float c = cosRow[dloc], s = sinRow[dloc];
    float r0 = a0 * c - a1 * s;
    float r1 = a1 * c + a0 * s;
    if (t < 128){
      qb_[i * 256 + 2 * pcol]     = r0;
      qb_[i * 256 + 2 * pcol + 1] = r1;
      int h = pcol >> 5;
#pragma unroll
      for (int cc = 0; cc < 8; ++cc){
        float pr = r0 * We[cc * 256 + 2 * pcol] + r1 * We[cc * 256 + 2 * pcol + 1];
#pragma unroll
        for (int m = 16; m >= 1; m >>= 1) pr += __shfl_xor(pr, m, 32);
        if ((t & 31) == 0) qWeB[(h * NTOK + i) * 8 + cc] = pr;
      }
      float pb = r0 * be[2 * pcol] + r1 * be[2 * pcol + 1];
#pragma unroll
      for (int m = 16; m >= 1; m >>= 1) pb += __shfl_xor(pb, m, 32);
      if ((t & 31) == 0) qbeB[h * NTOK + i] = pb;
    } else {
      int h = pcol >> 5, d0 = 2 * (pcol & 31);
      kbT[(size_t)(h * 64 + d0) * NTOK + i]     = r0;
      kbT[(size_t)(h * 64 + d0 + 1) * NTOK + i] = r1;
    }
  } else {
    vb_[i * 256 + 2 * pcol]     = a0;
    vb_[i * 256 + 2 * pcol + 1] = a1;
  }
}

// Layer-0: rotary (own row, into LDS + global table) + LN1 + QKV. 512 thr/row.
__global__ __launch_bounds__(512) void k_lnqkv(
    const float* __restrict__ x,
    const float* __restrict__ ls, const float* __restrict__ lb,
    const float* __restrict__ Wq, const float* __restrict__ bq,
    const float* __restrict__ Wkv, const float* __restrict__ bkv,
    const float* __restrict__ We, const float* __restrict__ be,
    float* __restrict__ cosS, float* __restrict__ sinS,
    float* __restrict__ qb_, float* __restrict__ kbT, float* __restrict__ vb_,
    float* __restrict__ qWeB, float* __restrict__ qbeB)
{
  __shared__ float snx[128];
  __shared__ float crow[64], srow[64];
  __shared__ float red[4];
  int i = swz_row(blockIdx.x);
  int t = threadIdx.x;

  // wave 7 computes rotary row i (doubles) while waves 0-1 do LN
  if (t >= 448){
    int d = t - 448;
    float c, s;
    rotary_val(i, d, &c, &s);
    crow[d] = c; srow[d] = s;
    cosS[i * 64 + d] = c; sinS[i * 64 + d] = s;
  }
  float xv = (t < 128) ? x[(size_t)i * 128 + t] : 0.f;
  float s = (t < 128) ? wave_sum64(xv) : 0.f;
  if (t == 0)  red[0] = s;
  if (t == 64) red[1] = s;
  __syncthreads();
  float mu = (red[0] + red[1]) * (1.0f / 128.0f);
  float d = xv - mu;
  float s2 = (t < 128) ? wave_sum64(d * d) : 0.f;
  if (t == 0)  red[2] = s2;
  if (t == 64) red[3] = s2;
  __syncthreads();
  if (t < 128){
    float var = (red[2] + red[3]) * (1.0f / 128.0f);
    float rstd = 1.0f / sqrtf(var + 1e-3f);
    snx[t] = d * rstd * ls[t] + lb[t];
  }
  __syncthreads();
  qkv_row_512(i, t, snx, Wq, bq, Wkv, bkv, We, be, crow, srow,
              qb_, kbT, vb_, qWeB, qbeB);
}

// Attention for one (i, h). 384 threads, thread t <-> j=t. K is transposed.
__global__ __launch_bounds__(384) void k_attn(
    const float* __restrict__ qb_, const float* __restrict__ kbT, const float* __restrict__ vb_,
    const float* __restrict__ qWeB, const float* __restrict__ qbeB,
    const float* __restrict__ edges,
    const float* __restrict__ We, const float* __restrict__ be,
    float* __restrict__ aout)
{
  __shared__ float qs[64];
  __shared__ float qw[8];
  __shared__ float qbs_s;
  __shared__ float attnL[NTOK];
  __shared__ float redA[6], redB[6];
  __shared__ float red8[6][8];
  __shared__ float aws[8];
  __shared__ float part[NTOK];

  int id = blockIdx.x;           // 1536 = 8 xcd * (48 rows * 4 heads)
  int xcd = id & 7, loc = id >> 3;
  int i = xcd * 48 + (loc % 48);
  int h = loc / 48;
  int t = threadIdx.x, lane = t & 63, wv = t >> 6;

  if (t < 64) qs[t] = qb_[i * 256 + h * 64 + t];
  else if (t < 72) qw[t - 64] = qWeB[(h * NTOK + i) * 8 + (t - 64)];
  else if (t == 72) qbs_s = qbeB[h * NTOK + i];
  __syncthreads();

  // ---- sim for j = t: coalesced reads of kbT[h][d][j]
  const float* kTp = kbT + (size_t)(h * 64) * NTOK + t;
  float ac0 = 0.f, ac1 = 0.f, ac2 = 0.f, ac3 = 0.f;
#pragma unroll 8
  for (int d = 0; d < 64; d += 4){
    ac0 = fmaf(qs[d],     kTp[(size_t)d * NTOK],       ac0);
    ac1 = fmaf(qs[d + 1], kTp[(size_t)(d + 1) * NTOK], ac1);
    ac2 = fmaf(qs[d + 2], kTp[(size_t)(d + 2) * NTOK], ac2);
    ac3 = fmaf(qs[d + 3], kTp[(size_t)(d + 3) * NTOK], ac3);
  }
  const float* ep = edges + ((size_t)i * NTOK + t) * 8;
  float4 e0 = *(const float4*)ep;
  float4 e1 = *(const float4*)(ep + 4);
  float ed = e0.x * qw[0] + e0.y * qw[1] + e0.z * qw[2] + e0.w * qw[3]
           + e1.x * qw[4] + e1.y * qw[5] + e1.z * qw[6] + e1.w * qw[7];
  float sim = 0.125f * (ac0 + ac1 + ac2 + ac3 + ed + qbs_s);

  // ---- softmax over 384 (6 waves)
  float mx = wave_max64(sim);
  if (lane == 0) redA[wv] = mx;
  __syncthreads();
  float gm = fmaxf(fmaxf(fmaxf(redA[0], redA[1]), fmaxf(redA[2], redA[3])),
                   fmaxf(redA[4], redA[5]));
  float e = expf(sim - gm);
  float sm = wave_sum64(e);
  if (lane == 0) redB[wv] = sm;
  __syncthreads();
  float tot = redB[0] + redB[1] + redB[2] + redB[3] + redB[4] + redB[5];
  float w = e / tot;
  attnL[t] = w;

  // ---- aw[c] = sum_j w[j]*edges[i,j,c]
  float a8[8] = { w * e0.x, w * e0.y, w * e0.z, w * e0.w,
                  w * e1.x, w * e1.y, w * e1.z, w * e1.w };
#pragma unroll
  for (int cc = 0; cc < 8; ++cc){
    float r = wave_sum64(a8[cc]);
    if (lane == 0) red8[wv][cc] = r;
  }
  __syncthreads();
  if (t < 8){
    float sa = 0.f;
#pragma unroll
    for (int g = 0; g < 6; ++g) sa += red8[g][t];
    aws[t] = sa;
  }
  __syncthreads();

  // ---- out[d] = sum_j attn[j]*v[j,d]  (6-way j split)
  {
    int dd = lane;
    const float* vp = vb_ + h * 64 + dd;
    int j0 = wv * 64;
    float va = 0.f, vb2 = 0.f;
#pragma unroll 8
    for (int jj = 0; jj < 64; jj += 2){
      va  = fmaf(attnL[j0 + jj],     vp[(size_t)(j0 + jj) * 256],     va);
      vb2 = fmaf(attnL[j0 + jj + 1], vp[(size_t)(j0 + jj + 1) * 256], vb2);
    }
    part[t] = va + vb2;
  }
  __syncthreads();
  if (t < 64){
    float o = part[t] + part[64 + t] + part[128 + t] + part[192 + t]
            + part[256 + t] + part[320 + t];
    float ew = 0.f;
#pragma unroll
    for (int cc = 0; cc < 8; ++cc) ew = fmaf(aws[cc], We[cc * 256 + h * 64 + t], ew);
    o += ew + be[h * 64 + t];
    aout[i * 256 + h * 64 + t] = o;
  }
}

// Fused tail: proj+gate+LN2+FFN+gate (+next-layer LN1+QKV). One row/block, 512 thr.
// GEMM stages: float4 weight loads, 4 cols/thread, in-block K-split. (R4 structure.)
__global__ __launch_bounds__(512) void k_tail(
    const float* __restrict__ aout,
    const float* __restrict__ Wo, const float* __restrict__ bo,
    const float* __restrict__ Wg_a,
    const float* __restrict__ ln2s, const float* __restrict__ ln2b,
    const float* __restrict__ W1, const float* __restrict__ b1,
    const float* __restrict__ W2, const float* __restrict__ b2,
    const float* __restrict__ Wg_f,
    const float* __restrict__ xin, float* __restrict__ xout,
    int has_next,
    const float* __restrict__ ls_n, const float* __restrict__ lb_n,
    const float* __restrict__ Wq_n, const float* __restrict__ bq_n,
    const float* __restrict__ Wkv_n, const float* __restrict__ bkv_n,
    const float* __restrict__ We_n, const float* __restrict__ be_n,
    const float* __restrict__ cosS, const float* __restrict__ sinS,
    float* __restrict__ qb_, float* __restrict__ kbT, float* __restrict__ vb_,
    float* __restrict__ qWeB, float* __restrict__ qbeB)
{
  __shared__ float ar[256];
  __shared__ float xold[128];
  __shared__ float xrow[128];
  __shared__ float snx[128];
  __shared__ float hs[512];
  __shared__ float4 prL[512];          // K-split partials
  __shared__ float red[4];
  float* prF = (float*)prL;

  int i = swz_row(blockIdx.x);
  int t = threadIdx.x;

  if (t < 64)            ((float4*)ar)[t]        = ((const float4*)(aout + (size_t)i * 256))[t];
  else if (t < 96)       ((float4*)xold)[t - 64] = ((const float4*)(xin + (size_t)i * 128))[t - 64];
  __syncthreads();

  // ---- proj: 128 outs, K=256. 32 colq x 16 ksub (16 k each).
  {
    int colq = t & 31, ksub = t >> 5;
    const float4* Wo4 = (const float4*)Wo;   // 32 float4 per row
    float4 acc = {0.f, 0.f, 0.f, 0.f};
#pragma unroll
    for (int kk = 0; kk < 16; ++kk){
      int k = ksub * 16 + kk;
      float4 w = Wo4[(size_t)k * 32 + colq];
      float a = ar[k];
      acc.x = fmaf(a, w.x, acc.x); acc.y = fmaf(a, w.y, acc.y);
      acc.z = fmaf(a, w.z, acc.z); acc.w = fmaf(a, w.w, acc.w);
    }
    prL[ksub * 32 + colq] = acc;
  }
  __syncthreads();

  // ---- reduce + gate_a + LN2 (2 waves)
  float o = 0.f;
  if (t < 128){
    o = bo[t];
#pragma unroll
    for (int s = 0; s < 16; ++s) o += prF[s * 128 + t];
    float xo = xold[t];
    float gp = o * Wg_a[t] + xo * Wg_a[128 + t] + (o - xo) * Wg_a[256 + t];
    float sg = wave_sum64(gp);
    if (t == 0)  red[0] = sg;
    if (t == 64) red[1] = sg;
  }
  __syncthreads();
  if (t < 128){
    float z = red[0] + red[1];
    float gg = 1.0f / (1.0f + expf(-z));
    xrow[t] = o * gg + xold[t] * (1.0f - gg);
  }
  __syncthreads();
  float xv2 = (t < 128) ? xrow[t] : 0.f;
  float s = (t < 128) ? wave_sum64(xv2) : 0.f;
  if (t == 0)  red[0] = s;
  if (t == 64) red[1] = s;
  __syncthreads();
  float mu = (red[0] + red[1]) * (1.0f / 128.0f);
  float dcen = xv2 - mu;
  float s2 = (t < 128) ? wave_sum64(dcen * dcen) : 0.f;
  if (t == 0)  red[2] = s2;
  if (t == 64) red[3] = s2;
  __syncthreads();
  if (t < 128){
    float var = (red[2] + red[3]) * (1.0f / 128.0f);
    float rstd = 1.0f / sqrtf(var + 1e-3f);
    snx[t] = dcen * rstd * ln2s[t] + ln2b[t];
  }
  __syncthreads();

  // ---- FFN1: 512 outs, K=128. 128 colq x 4 ksub (32 k each).
  {
    int colq = t & 127, ksub = t >> 7;
    const float4* W14 = (const float4*)W1;   // 128 float4 per row
    float4 acc = {0.f, 0.f, 0.f, 0.f};
#pragma unroll 8
    for (int kk = 0; kk < 32; ++kk){
      int k = ksub * 32 + kk;
      float4 w = W14[(size_t)k * 128 + colq];
      float a = snx[k];
      acc.x = fmaf(a, w.x, acc.x); acc.y = fmaf(a, w.y, acc.y);
      acc.z = fmaf(a, w.z, acc.z); acc.w = fmaf(a, w.w, acc.w);
    }
    prL[ksub * 128 + colq] = acc;
  }
  __syncthreads();

  // ---- reduce + GELU -> hs (512 threads, one col each)
  {
    float h = b1[t];
#pragma unroll
    for (int s3 = 0; s3 < 4; ++s3) h += prF[s3 * 512 + t];
    const float RS2 = 0.70710678118654752440f;
    hs[t] = 0.5f * h * (1.0f + erff(h * RS2));
  }
  __syncthreads();

  // ---- FFN2: 128 outs, K=512. 32 colq x 16 ksub (32 k each).
  {
    int colq = t & 31, ksub = t >> 5;
    const float4* W24 = (const float4*)W2;   // 32 float4 per row
    float4 acc = {0.f, 0.f, 0.f, 0.f};
#pragma unroll 8
    for (int kk = 0; kk < 32; ++kk){
      int k = ksub * 32 + kk;
      float4 w = W24[(size_t)k * 32 + colq];
      float a = hs[k];
      acc.x = fmaf(a, w.x, acc.x); acc.y = fmaf(a, w.y, acc.y);
      acc.z = fmaf(a, w.z, acc.z); acc.w = fmaf(a, w.w, acc.w);
    }
    prL[ksub * 32 + colq] = acc;
  }
  __syncthreads();

  // ---- reduce + gate_f + write xnew + next-layer LN1 (2 waves)
  float f = 0.f;
  if (t < 128){
    f = b2[t];
#pragma unroll
    for (int s3 = 0; s3 < 16; ++s3) f += prF[s3 * 128 + t];
    float xr = xrow[t];
    float gp = f * Wg_f[t] + xr * Wg_f[128 + t] + (f - xr) * Wg_f[256 + t];
    float sg = wave_sum64(gp);
    if (t == 0)  red[0] = sg;
    if (t == 64) red[1] = sg;
  }
  __syncthreads();
  float xnew = 0.f;
  if (t < 128){
    float z = red[0] + red[1];
    float gg = 1.0f / (1.0f + expf(-z));
    xnew = f * gg + xrow[t] * (1.0f - gg);
    xout[(size_t)i * 128 + t] = xnew;
  }
  if (has_next){
    float sn = (t < 128) ? wave_sum64(xnew) : 0.f;
    if (t == 0)  red[0] = sn;
    if (t == 64) red[1] = sn;
    __syncthreads();
    float mun = (red[0] + red[1]) * (1.0f / 128.0f);
    float dn = xnew - mun;
    float sn2 = (t < 128) ? wave_sum64(dn * dn) : 0.f;
    if (t == 0)  red[2] = sn2;
    if (t == 64) red[3] = sn2;
    __syncthreads();
    if (t < 128){
      float var = (red[2] + red[3]) * (1.0f / 128.0f);
      float rstd = 1.0f / sqrtf(var + 1e-3f);
      snx[t] = dn * rstd * ls_n[t] + lb_n[t];
    }
    __syncthreads();
    qkv_row_512(i, t, snx, Wq_n, bq_n, Wkv_n, bkv_n, We_n, be_n,
                cosS + (size_t)i * 64, sinS + (size_t)i * 64,
                qb_, kbT, vb_, qWeB, qbeB);
  }
}

// Final head. Single block, 384 threads, float4 x loads.
__global__ __launch_bounds__(384) void k_final(
    const float* __restrict__ x,
    const float* __restrict__ Wd1, const float* __restrict__ bd1,
    const float* __restrict__ Wd2, const float* __restrict__ bd2,
    float* __restrict__ out)
{
  __shared__ float red[6];
  int i = threadIdx.x;
  float y[9];
#pragma unroll
  for (int c = 0; c < 9; ++c) y[c] = bd1[c];
  const float4* x4 = (const float4*)(x + (size_t)i * 128);
#pragma unroll 8
  for (int r4 = 0; r4 < 32; ++r4){
    float4 xv = x4[r4];
    const float* wp = Wd1 + (r4 * 4) * 9;
#pragma unroll
    for (int c = 0; c < 9; ++c) y[c] = fmaf(xv.x, wp[c], y[c]);
#pragma unroll
    for (int c = 0; c < 9; ++c) y[c] = fmaf(xv.y, wp[9 + c], y[c]);
#pragma unroll
    for (int c = 0; c < 9; ++c) y[c] = fmaf(xv.z, wp[18 + c], y[c]);
#pragma unroll
    for (int c = 0; c < 9; ++c) y[c] = fmaf(xv.w, wp[27 + c], y[c]);
  }
#pragma unroll
  for (int c = 0; c < 9; ++c) y[c] = fmaxf(y[c], 0.0f);
  float z[3];
#pragma unroll
  for (int c = 0; c < 3; ++c){
    float a = bd2[c];
#pragma unroll
    for (int r = 0; r < 9; ++r) a = fmaf(y[r], Wd2[r * 3 + c], a);
    z[c] = a;
  }
#pragma unroll
  for (int c = 0; c < 3; ++c){
    float s = wave_sum64(z[c]);
    if ((i & 63) == 0) red[i >> 6] = s;
    __syncthreads();
    float tot = 0.f;
#pragma unroll
    for (int w = 0; w < 6; ++w) tot += red[w];
    float mean = tot * (1.0f / 384.0f);
    out[i * 3 + c] = z[c] - mean;
    __syncthreads();
  }
}

extern "C" void kernel_launch(void* const* d_in, const int* in_sizes, int n_in,
                              void* d_out, int out_size, void* d_ws, size_t ws_size,
                              hipStream_t stream)
{
  const float* nodes   = (const float*)d_in[0];
  const float* edges   = (const float*)d_in[1];
  const float* ln1_s   = (const float*)d_in[2];
  const float* ln1_b   = (const float*)d_in[3];
  const float* Wq      = (const float*)d_in[4];
  const float* bq      = (const float*)d_in[5];
  const float* Wkv     = (const float*)d_in[6];
  const float* bkv     = (const float*)d_in[7];
  const float* We      = (const float*)d_in[8];
  const float* be      = (const float*)d_in[9];
  const float* Wo      = (const float*)d_in[10];
  const float* bo      = (const float*)d_in[11];
  const float* Wg_attn = (const float*)d_in[12];
  const float* ln2_s   = (const float*)d_in[13];
  const float* ln2_b   = (const float*)d_in[14];
  const float* W1      = (const float*)d_in[15];
  const float* b1      = (const float*)d_in[16];
  const float* W2      = (const float*)d_in[17];
  const float* b2      = (const float*)d_in[18];
  const float* Wg_ff   = (const float*)d_in[19];
  const float* Wd1     = (const float*)d_in[20];
  const float* bd1     = (const float*)d_in[21];
  const float* Wd2     = (const float*)d_in[22];
  const float* bd2     = (const float*)d_in[23];
  // d_in[24] = mask: all-true; no-op in the math.

  float* ws   = (float*)d_ws;
  float* cosS = ws;                 // 384*64
  float* sinS = cosS + 24576;
  float* qbuf = sinS + 24576;       // 384*256
  float* kbT  = qbuf + 98304;       // [4][64][384]
  float* vbuf = kbT + 98304;
  float* qWeB = vbuf + 98304;       // 4*384*8
  float* qbeB = qWeB + 12288;       // 4*384
  float* aoutB = qbeB + 1536;       // 384*256
  float* xbuf = aoutB + 98304;      // 384*128

  k_lnqkv<<<dim3(NTOK), dim3(512), 0, stream>>>(
      nodes, ln1_s, ln1_b, Wq, bq, Wkv, bkv, We, be,
      cosS, sinS, qbuf, kbT, vbuf, qWeB, qbeB);

  for (int L = 0; L < DEPTH; ++L){
    int Ln = (L < DEPTH - 1) ? (L + 1) : L;
    k_attn<<<dim3(NTOK * HEADS), dim3(384), 0, stream>>>(
        qbuf, kbT, vbuf, qWeB, qbeB, edges,
        We + (size_t)L * EDGE * INNER, be + L * INNER, aoutB);
    k_tail<<<dim3(NTOK), dim3(512), 0, stream>>>(
        aoutB, Wo + (size_t)L * INNER * DIM, bo + L * DIM,
        Wg_attn + L * 3 * DIM,
        ln2_s + L * DIM, ln2_b + L * DIM,
        W1 + (size_t)L * DIM * FFD, b1 + L * FFD,
        W2 + (size_t)L * FFD * DIM, b2 + L * DIM,
        Wg_ff + L * 3 * DIM,
        (L == 0) ? nodes : xbuf, xbuf,
        (L < DEPTH - 1) ? 1 : 0,
        ln1_s + Ln * DIM, ln1_b + Ln * DIM,
        Wq + (size_t)Ln * DIM * INNER, bq + Ln * INNER,
        Wkv + (size_t)Ln * DIM * 2 * INNER, bkv + Ln * 2 * INNER,
        We + (size_t)Ln * EDGE * INNER, be + Ln * INNER,
        cosS, sinS, qbuf, kbT, vbuf, qWeB, qbeB);
  }

  k_final<<<dim3(1), dim3(384), 0, stream>>>(xbuf, Wd1, bd1, Wd2, bd2, (float*)d_out);
}